// Round 7
// baseline (1196.317 us; speedup 1.0000x reference)
//
#include <hip/hip_runtime.h>
#include <hip/hip_bf16.h>
#include <math.h>

#define D_MODEL 3072
#define N_HEADS 24
#define DH 128
#define L_TXT 256
#define L_IMG 1024
#define L_ALL 1280
#define N_QKV 9216
#define N_MLP 12288
#define MOD_N 18432

typedef __attribute__((ext_vector_type(4))) float f32x4;
typedef __attribute__((ext_vector_type(8))) short bf16x8;

static __device__ __forceinline__ unsigned short f2bf(float f) {
  __hip_bfloat16 h = __float2bfloat16(f);
  union { __hip_bfloat16 h; unsigned short u; } v; v.h = h;
  return v.u;
}
static __device__ __forceinline__ unsigned pack2(float a, float b) {
  return (unsigned)f2bf(a) | ((unsigned)f2bf(b) << 16);
}

// ---------------------------------------------------------------- small ops
__global__ void silu_kernel(const float* __restrict__ vec, float* __restrict__ s) {
  int i = blockIdx.x * 256 + threadIdx.x;
  if (i < D_MODEL) { float x = vec[i]; s[i] = x / (1.f + expf(-x)); }
}

// float4-vectorized: thread owns 4 consecutive cols. grid (18, 16, 2)
__global__ __launch_bounds__(256) void mod_gemv_partial(
    const float* __restrict__ s, const float* __restrict__ w_img,
    const float* __restrict__ w_txt, float* __restrict__ part) {
  int col4 = blockIdx.x * 256 + threadIdx.x;  // 0..4607
  int kb = blockIdx.y;
  const float4* w4 = (const float4*)(blockIdx.z == 0 ? w_img : w_txt);
  float4 acc = {0.f, 0.f, 0.f, 0.f};
  int k0 = kb * 192;
  #pragma unroll 4
  for (int j = 0; j < 192; ++j) {
    float sv = s[k0 + j];
    float4 wv = w4[(size_t)(k0 + j) * 4608 + col4];
    acc.x = fmaf(sv, wv.x, acc.x);
    acc.y = fmaf(sv, wv.y, acc.y);
    acc.z = fmaf(sv, wv.z, acc.z);
    acc.w = fmaf(sv, wv.w, acc.w);
  }
  ((float4*)part)[(size_t)(blockIdx.z * 16 + kb) * 4608 + col4] = acc;
}

__global__ void mod_reduce(const float* __restrict__ part,
                           const float* __restrict__ b_img,
                           const float* __restrict__ b_txt,
                           float* __restrict__ modv) {
  int i = blockIdx.x * 256 + threadIdx.x;
  int st = i / MOD_N, col = i - st * MOD_N;
  float a = (st == 0) ? b_img[col] : b_txt[col];
  #pragma unroll
  for (int p = 0; p < 16; ++p) a += part[(st * 16 + p) * MOD_N + col];
  modv[i] = a;
}

// LN over D=3072 then (1+scale)*ln + shift, write bf16
__global__ __launch_bounds__(256) void ln_mod_kernel(
    const float* __restrict__ x, unsigned short* __restrict__ xm,
    const float* __restrict__ modv, int sh_off, int sc_off) {
  int row = blockIdx.x, t = threadIdx.x;
  int lane = t & 63, wid = t >> 6;
  const float4* xr = (const float4*)(x + (size_t)row * D_MODEL);
  float4 a = xr[t], b = xr[t + 256], c = xr[t + 512];
  float s = a.x + a.y + a.z + a.w + b.x + b.y + b.z + b.w + c.x + c.y + c.z + c.w;
  float q = a.x * a.x + a.y * a.y + a.z * a.z + a.w * a.w
          + b.x * b.x + b.y * b.y + b.z * b.z + b.w * b.w
          + c.x * c.x + c.y * c.y + c.z * c.z + c.w * c.w;
  #pragma unroll
  for (int m = 1; m < 64; m <<= 1) { s += __shfl_xor(s, m); q += __shfl_xor(q, m); }
  __shared__ float red[8];
  if (lane == 0) { red[wid] = s; red[4 + wid] = q; }
  __syncthreads();
  s = red[0] + red[1] + red[2] + red[3];
  q = red[4] + red[5] + red[6] + red[7];
  float mean = s * (1.f / 3072.f);
  float var = q * (1.f / 3072.f) - mean * mean;
  float inv = 1.f / sqrtf(var + 1e-6f);
  const float4* shp = (const float4*)(modv + sh_off);
  const float4* scp = (const float4*)(modv + sc_off);
  uint2* outp = (uint2*)(xm + (size_t)row * D_MODEL);
  float4 vals[3] = {a, b, c};
  #pragma unroll
  for (int j = 0; j < 3; ++j) {
    float4 sh = shp[t + j * 256], sc = scp[t + j * 256];
    float4 v = vals[j];
    float y0 = (v.x - mean) * inv * (1.f + sc.x) + sh.x;
    float y1 = (v.y - mean) * inv * (1.f + sc.y) + sh.y;
    float y2 = (v.z - mean) * inv * (1.f + sc.z) + sh.z;
    float y3 = (v.w - mean) * inv * (1.f + sc.w) + sh.w;
    uint2 o; o.x = pack2(y0, y1); o.y = pack2(y2, y3);
    outp[t + j * 256] = o;
  }
}

// ---------------------------------------------------------------- GEMM v7
// 256 thr / 4 waves, tile 128M x 128N, BK=32. Only W lives in LDS (bf16,
// k-octet layout [koct][n][8] with 16B pad per koct-row -> all fragment
// reads are conflict-free ds_read_b128). W staged global->reg (16 coalesced
// f32 loads/thread) -> cvt_pk -> 2x ds_write_b128, double-buffered, 2-deep
// register prefetch (wA/wB, statically indexed). A (bf16) fragments load
// DIRECTLY from global (k-contiguous 16B, L2-served with high reuse).
// One barrier per K-step. ~150 VGPR, 3 waves/SIMD, 16.5KB LDS.
// EPI 0: +bias -> f32   EPI 1: +bias, gelu -> bf16   EPI 3: raw partial -> f32
template <int EPI>
__global__ __launch_bounds__(256, 3) void gemm7_kernel(
    const unsigned short* __restrict__ A0, const float* __restrict__ W0,
    const float* __restrict__ b0, float* __restrict__ oF0,
    float* __restrict__ oF0b, unsigned short* __restrict__ oB0,
    const unsigned short* __restrict__ A1, const float* __restrict__ W1,
    const float* __restrict__ b1, float* __restrict__ oF1,
    float* __restrict__ oF1b, unsigned short* __restrict__ oB1,
    int mi, int mt, int N, int Ktot, int Kper) {
  // per buffer: 4 kocts x (128 cols * 8 + 8 pad) shorts = 4128 shorts
  __shared__ __align__(16) unsigned short Wlds[2 * 4128];

  const int MT = mi + mt;
  const int q8 = gridDim.x >> 3;  // grid % 8 == 0 by construction
  int orig = (blockIdx.x & 7) * q8 + (blockIdx.x >> 3);
  const int per_k = (N >> 7) * MT;
  const int kz = orig / per_k; orig -= kz * per_k;
  const int ntile = orig / MT;
  const int mrem = orig - ntile * MT;

  const unsigned short* A; const float* W; const float* bias;
  float* outF; unsigned short* outB; int brow;
  if (mrem < mi) {
    A = A0; W = W0; bias = b0; outF = kz ? oF0b : oF0; outB = oB0; brow = mrem * 128;
  } else {
    A = A1; W = W1; bias = b1; outF = kz ? oF1b : oF1; outB = oB1; brow = (mrem - mi) * 128;
  }
  const int bcol = ntile * 128;
  const int k0base = kz * Kper;

  const int tid = threadIdx.x, lane = tid & 63, wid = tid >> 6;
  const int lm = lane & 15, lk = lane >> 4;
  const int wr = (wid >> 1) * 64, wc = (wid & 1) * 64;

  const int koct0 = tid >> 7;   // 0 or 1 (cells at koct0, koct0+2)
  const int ncol = tid & 127;   // 0..127
  const size_t Ns = (size_t)N;
  const float* wgp = W + bcol + ncol;
  const unsigned short* apb =
      A + (size_t)(brow + wr + lm) * Ktot + k0base + lk * 8;

  f32x4 acc[4][4] = {};
  float wA[16], wB[16];
  const int nt = Kper >> 5;

  auto LOADW = [&](float (&w)[16], int t) {
    const size_t kb = (size_t)(k0base + t * 32) * Ns;
    #pragma unroll
    for (int c = 0; c < 2; ++c) {
      const size_t cb = kb + (size_t)((koct0 + 2 * c) * 8) * Ns;
      #pragma unroll
      for (int i = 0; i < 8; ++i)
        w[c * 8 + i] = wgp[cb + (size_t)i * Ns];
    }
  };
  auto PACKW = [&](int buf, float (&w)[16]) {
    #pragma unroll
    for (int c = 0; c < 2; ++c) {
      uint4 p;
      p.x = pack2(w[c * 8 + 0], w[c * 8 + 1]);
      p.y = pack2(w[c * 8 + 2], w[c * 8 + 3]);
      p.z = pack2(w[c * 8 + 4], w[c * 8 + 5]);
      p.w = pack2(w[c * 8 + 6], w[c * 8 + 7]);
      *(uint4*)&Wlds[buf * 4128 + (koct0 + 2 * c) * 1032 + ncol * 8] = p;
    }
  };
  auto COMPUTE = [&](int buf, int t) {
    bf16x8 bfr[4];
    #pragma unroll
    for (int nf = 0; nf < 4; ++nf)
      bfr[nf] = *(const bf16x8*)&Wlds[buf * 4128 + lk * 1032 + (wc + nf * 16 + lm) * 8];
    bf16x8 af[4];
    #pragma unroll
    for (int mf = 0; mf < 4; ++mf)
      af[mf] = *(const bf16x8*)(apb + (size_t)mf * 16 * Ktot + t * 32);
    #pragma unroll
    for (int mf = 0; mf < 4; ++mf)
      #pragma unroll
      for (int nf = 0; nf < 4; ++nf)
        acc[mf][nf] = __builtin_amdgcn_mfma_f32_16x16x32_bf16(af[mf], bfr[nf], acc[mf][nf], 0, 0, 0);
  };

  // prologue: wA <- t0, wB <- t1, stage t0 into buf0
  LOADW(wA, 0);
  LOADW(wB, 1);
  PACKW(0, wA);
  __syncthreads();
  for (int t = 0; t < nt; t += 2) {
    if (t + 2 < nt) LOADW(wA, t + 2);
    PACKW(1, wB);               // stage t+1 into buf1 (while buf0 is read)
    COMPUTE(0, t);
    __syncthreads();
    if (t + 3 < nt) LOADW(wB, t + 3);
    if (t + 2 < nt) PACKW(0, wA); // stage t+2 into buf0 (while buf1 is read)
    COMPUTE(1, t + 1);
    __syncthreads();
  }

  #pragma unroll
  for (int nf = 0; nf < 4; ++nf) {
    int c = bcol + wc + nf * 16 + lm;
    float bv = (EPI == 3) ? 0.f : bias[c];
    #pragma unroll
    for (int mf = 0; mf < 4; ++mf) {
      int r0 = brow + wr + mf * 16 + lk * 4;
      #pragma unroll
      for (int rg = 0; rg < 4; ++rg) {
        float v = acc[mf][nf][rg] + bv;
        size_t idx = (size_t)(r0 + rg) * N + c;
        if (EPI == 0) {
          outF[idx] = v;
        } else if (EPI == 1) {
          float g = 0.5f * v * (1.f + tanhf(0.7978845608028654f * (v + 0.044715f * v * v * v)));
          outB[idx] = f2bf(g);
        } else {
          outF[idx] = v;
        }
      }
    }
  }
}

// out = res + gate * (s0 + s1 + bias), float4-vectorized
__global__ __launch_bounds__(256) void split_reduce_kernel(
    const float* __restrict__ s0, const float* __restrict__ s1,
    const float* __restrict__ res, const float* __restrict__ bias,
    const float* __restrict__ gate, float* __restrict__ out,
    int n4, int ncol4) {
  int i = blockIdx.x * 256 + threadIdx.x;
  if (i >= n4) return;
  int c4 = i % ncol4;
  float4 a = ((const float4*)s0)[i];
  float4 b = ((const float4*)s1)[i];
  float4 bv = ((const float4*)bias)[c4];
  float4 gv = ((const float4*)gate)[c4];
  float4 rv = ((const float4*)res)[i];
  float4 o;
  o.x = rv.x + gv.x * (a.x + b.x + bv.x);
  o.y = rv.y + gv.y * (a.y + b.y + bv.y);
  o.z = rv.z + gv.z * (a.z + b.z + bv.z);
  o.w = rv.w + gv.w * (a.w + b.w + bv.w);
  ((float4*)out)[i] = o;
}

// ---------------------------------------------------------------- rms+rope+pack
__global__ __launch_bounds__(256) void rms_rope_kernel(
    const float* __restrict__ qkv_img, const float* __restrict__ qkv_txt,
    const float* __restrict__ img_qn, const float* __restrict__ img_kn,
    const float* __restrict__ txt_qn, const float* __restrict__ txt_kn,
    const float* __restrict__ pe, unsigned short* __restrict__ qa,
    unsigned short* __restrict__ ka, unsigned short* __restrict__ va) {
  int l = blockIdx.x * 4 + (threadIdx.x >> 6);
  int h = blockIdx.y;
  int t = threadIdx.x & 63;
  const float* base; const float* qn; const float* kn;
  if (l < L_TXT) { base = qkv_txt + (size_t)l * N_QKV; qn = txt_qn; kn = txt_kn; }
  else { base = qkv_img + (size_t)(l - L_TXT) * N_QKV; qn = img_qn; kn = img_kn; }
  int d0 = 2 * t;
  float q0 = base[h * DH + d0], q1 = base[h * DH + d0 + 1];
  float k0 = base[D_MODEL + h * DH + d0], k1 = base[D_MODEL + h * DH + d0 + 1];
  float v0 = base[2 * D_MODEL + h * DH + d0], v1 = base[2 * D_MODEL + h * DH + d0 + 1];
  float sq = q0 * q0 + q1 * q1, sk = k0 * k0 + k1 * k1;
  #pragma unroll
  for (int m = 1; m < 64; m <<= 1) { sq += __shfl_xor(sq, m); sk += __shfl_xor(sk, m); }
  float rq = 1.f / sqrtf(sq * (1.f / 128.f) + 1e-6f);
  float rk = 1.f / sqrtf(sk * (1.f / 128.f) + 1e-6f);
  q0 *= rq * qn[d0]; q1 *= rq * qn[d0 + 1];
  k0 *= rk * kn[d0]; k1 *= rk * kn[d0 + 1];
  const float* p = pe + ((size_t)l * 64 + t) * 4;
  float p00 = p[0], p01 = p[1], p10 = p[2], p11 = p[3];
  const float sc = 0.08838834764831845f; // 1/sqrt(128), folded into q
  float Q0 = (p00 * q0 + p01 * q1) * sc;
  float Q1 = (p10 * q0 + p11 * q1) * sc;
  float K0 = p00 * k0 + p01 * k1;
  float K1 = p10 * k0 + p11 * k1;
  size_t o = ((size_t)h * L_ALL + l) * 64 + t;
  ((unsigned*)qa)[o] = pack2(Q0, Q1);
  ((unsigned*)ka)[o] = pack2(K0, K1);
  ((unsigned*)va)[o] = pack2(v0, v1);
}

// ---------------------------------------------------------------- attention
static __device__ __forceinline__ void stage_v8(unsigned short* vp, int n0, uint4 v) {
  vp[(n0 + 0) * 8] = (unsigned short)v.x; vp[(n0 + 1) * 8] = (unsigned short)(v.x >> 16);
  vp[(n0 + 2) * 8] = (unsigned short)v.y; vp[(n0 + 3) * 8] = (unsigned short)(v.y >> 16);
  vp[(n0 + 4) * 8] = (unsigned short)v.z; vp[(n0 + 5) * 8] = (unsigned short)(v.z >> 16);
  vp[(n0 + 6) * 8] = (unsigned short)v.w; vp[(n0 + 7) * 8] = (unsigned short)(v.w >> 16);
}

__global__ __launch_bounds__(256) void attn_kernel(
    const unsigned short* __restrict__ qa, const unsigned short* __restrict__ ka,
    const unsigned short* __restrict__ va, unsigned short* __restrict__ out) {
  __shared__ __align__(16) unsigned short Ks[64 * 136];
  __shared__ __align__(16) unsigned short Vs[16 * 128 * 8]; // [kv/8][d][kv&7]
  __shared__ __align__(16) unsigned short Ps[4][16 * 72];
  int h = blockIdx.y, qt = blockIdx.x;
  int tid = threadIdx.x, lane = tid & 63, wid = tid >> 6;
  int lm = lane & 15, lk = lane >> 4;
  const unsigned short* qh = qa + (size_t)h * L_ALL * DH;
  const unsigned short* kh = ka + (size_t)h * L_ALL * DH;
  const unsigned short* vh = va + (size_t)h * L_ALL * DH;

  int qrow = qt * 64 + wid * 16 + lm;
  bf16x8 qf[4];
  #pragma unroll
  for (int kk = 0; kk < 4; ++kk)
    qf[kk] = *(const bf16x8*)(qh + (size_t)qrow * DH + kk * 32 + lk * 8);

  float m_run[4] = {-INFINITY, -INFINITY, -INFINITY, -INFINITY};
  float s_run[4] = {0.f, 0.f, 0.f, 0.f};
  f32x4 o[8] = {};

  int sr = tid >> 2, sc = (tid & 3) * 32; // staging: row, col0 (elems)

  for (int kt = 0; kt < L_ALL / 64; ++kt) {
    const uint4* kg = (const uint4*)(kh + (size_t)(kt * 64 + sr) * DH + sc);
    uint4 kv0 = kg[0], kv1 = kg[1], kv2 = kg[2], kv3 = kg[3];
    const uint4* vg = (const uint4*)(vh + (size_t)(kt * 64 + sr) * DH + sc);
    uint4 vv0 = vg[0], vv1 = vg[1], vv2 = vg[2], vv3 = vg[3];
    __syncthreads();
    uint4* kd = (uint4*)(&Ks[sr * 136 + sc]);
    kd[0] = kv0; kd[1] = kv1; kd[2] = kv2; kd[3] = kv3;
    {
      unsigned short* vp = &Vs[(sr >> 3) * 1024 + (sr & 7)];
      stage_v8(vp, sc, vv0); stage_v8(vp, sc + 8, vv1);
      stage_v8(vp, sc + 16, vv2); stage_v8(vp, sc + 24, vv3);
    }
    __syncthreads();

    f32x4 S[4] = {};
    #pragma unroll
    for (int kk = 0; kk < 4; ++kk)
      #pragma unroll
      for (int nf = 0; nf < 4; ++nf) {
        bf16x8 bv = *(const bf16x8*)(&Ks[(nf * 16 + lm) * 136 + kk * 32 + lk * 8]);
        S[nf] = __builtin_amdgcn_mfma_f32_16x16x32_bf16(qf[kk], bv, S[nf], 0, 0, 0);
      }

    float corr[4];
    #pragma unroll
    for (int r = 0; r < 4; ++r) {
      float mx = fmaxf(fmaxf(S[0][r], S[1][r]), fmaxf(S[2][r], S[3][r]));
      mx = fmaxf(mx, __shfl_xor(mx, 1));
      mx = fmaxf(mx, __shfl_xor(mx, 2));
      mx = fmaxf(mx, __shfl_xor(mx, 4));
      mx = fmaxf(mx, __shfl_xor(mx, 8));
      float mn = fmaxf(m_run[r], mx);
      corr[r] = expf(m_run[r] - mn);
      m_run[r] = mn;
    }
    float rs[4] = {0.f, 0.f, 0.f, 0.f};
    float pv[4][4];
    #pragma unroll
    for (int nf = 0; nf < 4; ++nf)
      #pragma unroll
      for (int r = 0; r < 4; ++r) {
        pv[nf][r] = expf(S[nf][r] - m_run[r]);
        rs[r] += pv[nf][r];
      }
    #pragma unroll
    for (int nf = 0; nf < 4; ++nf)
      #pragma unroll
      for (int r = 0; r < 4; ++r)
        Ps[wid][(lk * 4 + r) * 72 + nf * 16 + lm] = f2bf(pv[nf][r]);
    #pragma unroll
    for (int r = 0; r < 4; ++r) {
      rs[r] += __shfl_xor(rs[r], 1);
      rs[r] += __shfl_xor(rs[r], 2);
      rs[r] += __shfl_xor(rs[r], 4);
      rs[r] += __shfl_xor(rs[r], 8);
      s_run[r] = s_run[r] * corr[r] + rs[r];
    }
    #pragma unroll
    for (int nf = 0; nf < 8; ++nf)
      #pragma unroll
      for (int r = 0; r < 4; ++r)
        o[nf][r] *= corr[r];

    #pragma unroll
    for (int kk2 = 0; kk2 < 2; ++kk2) {
      bf16x8 pa = *(const bf16x8*)(&Ps[wid][lm * 72 + kk2 * 32 + lk * 8]);
      #pragma unroll
      for (int nf = 0; nf < 8; ++nf) {
        bf16x8 vb = *(const bf16x8*)(&Vs[((kk2 * 4 + lk) * 128 + nf * 16 + lm) * 8]);
        o[nf] = __builtin_amdgcn_mfma_f32_16x16x32_bf16(pa, vb, o[nf], 0, 0, 0);
      }
    }
  }

  float inv[4];
  #pragma unroll
  for (int r = 0; r < 4; ++r) inv[r] = 1.f / s_run[r];
  #pragma unroll
  for (int nf = 0; nf < 8; ++nf)
    #pragma unroll
    for (int r = 0; r < 4; ++r) {
      int row = qt * 64 + wid * 16 + lk * 4 + r;
      int col = h * DH + nf * 16 + lm;
      out[(size_t)row * D_MODEL + col] = f2bf(o[nf][r] * inv[r]);
    }
}

// ---------------------------------------------------------------- launch
extern "C" void kernel_launch(void* const* d_in, const int* in_sizes, int n_in,
                              void* d_out, int out_size, void* d_ws, size_t ws_size,
                              hipStream_t stream) {
  const float* img = (const float*)d_in[0];
  const float* txt = (const float*)d_in[1];
  const float* vec = (const float*)d_in[2];
  const float* pe = (const float*)d_in[3];
  const float* img_mod_w = (const float*)d_in[4];
  const float* img_mod_b = (const float*)d_in[5];
  const float* img_qkv_w = (const float*)d_in[6];
  const float* img_qkv_b = (const float*)d_in[7];
  const float* img_qnorm = (const float*)d_in[8];
  const float* img_knorm = (const float*)d_in[9];
  const float* img_proj_w = (const float*)d_in[10];
  const float* img_proj_b = (const float*)d_in[11];
  const float* img_mlp_w1 = (const float*)d_in[12];
  const float* img_mlp_b1 = (const float*)d_in[13];
  const float* img_mlp_w2 = (const float*)d_in[14];
  const float* img_mlp_b2 = (const float*)d_in[15];
  const float* txt_mod_w = (const float*)d_in[16];
  const float* txt_mod_b = (const float*)d_in[17];
  const float* txt_qkv_w = (const float*)d_in[18];
  const float* txt_qkv_b = (const float*)d_in[19];
  const float* txt_qnorm = (const float*)d_in[20];
  const float* txt_knorm = (const float*)d_in[21];
  const float* txt_proj_w = (const float*)d_in[22];
  const float* txt_proj_b = (const float*)d_in[23];
  const float* txt_mlp_w1 = (const float*)d_in[24];
  const float* txt_mlp_b1 = (const float*)d_in[25];
  const float* txt_mlp_w2 = (const float*)d_in[26];
  const float* txt_mlp_b2 = (const float*)d_in[27];

  char* wsb = (char*)d_ws;
  float* silu_s = (float*)(wsb + 0);
  float* part = (float*)(wsb + 16384);
  float* modv = (float*)(wsb + 2375680);
  unsigned short* xm_img = (unsigned short*)(wsb + 2523136);
  unsigned short* xm_txt = xm_img + (size_t)L_IMG * D_MODEL;
  float* qkv_img = (float*)(wsb + 10387456);
  float* qkv_txt = qkv_img + (size_t)L_IMG * N_QKV;
  unsigned short* qa = (unsigned short*)(wsb + 57573376);
  unsigned short* ka = (unsigned short*)(wsb + 65437696);
  unsigned short* va = (unsigned short*)(wsb + 73302016);
  unsigned short* attn = xm_img;                       // xm dead
  float* img2 = (float*)(wsb + 10387456);              // qkv dead
  float* txt2 = img2 + (size_t)L_IMG * D_MODEL;
  float* pslab = (float*)(wsb + 26116096);             // proj partials (2x 15.73MB)
  float* pslab1 = pslab + (size_t)L_ALL * D_MODEL;
  unsigned short* h_img = (unsigned short*)(wsb + 26116096); // after proj reduce
  unsigned short* h_txt = h_img + (size_t)L_IMG * N_MLP;
  unsigned short* xm2_img = qa;                        // qa dead after attn
  unsigned short* xm2_txt = xm2_img + (size_t)L_IMG * D_MODEL;
  float* m2slab1 = (float*)(wsb + 57573376);           // mlp2 slab1 (xm2 dead)
  float* out_img = (float*)d_out;
  float* out_txt = out_img + (size_t)L_IMG * D_MODEL;
  float* mod_img = modv;
  float* mod_txt = modv + MOD_N;

  silu_kernel<<<12, 256, 0, stream>>>(vec, silu_s);
  mod_gemv_partial<<<dim3(18, 16, 2), 256, 0, stream>>>(silu_s, img_mod_w, txt_mod_w, part);
  mod_reduce<<<144, 256, 0, stream>>>(part, img_mod_b, txt_mod_b, modv);
  ln_mod_kernel<<<L_IMG, 256, 0, stream>>>(img, xm_img, mod_img, 0, 3072);
  ln_mod_kernel<<<L_TXT, 256, 0, stream>>>(txt, xm_txt, mod_txt, 0, 3072);

  // qkv: NT=72, MT=10 -> 720 blocks
  gemm7_kernel<0><<<720, 256, 0, stream>>>(
      xm_img, img_qkv_w, img_qkv_b, qkv_img, qkv_img, nullptr,
      xm_txt, txt_qkv_w, txt_qkv_b, qkv_txt, qkv_txt, nullptr,
      8, 2, N_QKV, D_MODEL, D_MODEL);

  rms_rope_kernel<<<dim3(L_ALL / 4, N_HEADS), 256, 0, stream>>>(qkv_img, qkv_txt, img_qnorm, img_knorm, txt_qnorm, txt_knorm, pe, qa, ka, va);
  attn_kernel<<<dim3(L_ALL / 64, N_HEADS), 256, 0, stream>>>(qa, ka, va, attn);

  // proj: NT=24, MT=10, ksplit2 -> 480 blocks, Kper=1536
  gemm7_kernel<3><<<480, 256, 0, stream>>>(
      attn + (size_t)L_TXT * D_MODEL, img_proj_w, img_proj_b, pslab, pslab1, nullptr,
      attn, txt_proj_w, txt_proj_b, pslab + (size_t)L_IMG * D_MODEL, pslab1 + (size_t)L_IMG * D_MODEL, nullptr,
      8, 2, D_MODEL, D_MODEL, 1536);
  split_reduce_kernel<<<3072, 256, 0, stream>>>(
      pslab, pslab1, img, img_proj_b, mod_img + 6144, img2, L_IMG * 768, 768);
  split_reduce_kernel<<<768, 256, 0, stream>>>(
      pslab + (size_t)L_IMG * D_MODEL, pslab1 + (size_t)L_IMG * D_MODEL, txt, txt_proj_b, mod_txt + 6144, txt2, L_TXT * 768, 768);

  ln_mod_kernel<<<L_IMG, 256, 0, stream>>>(img2, xm2_img, mod_img, 9216, 12288);
  ln_mod_kernel<<<L_TXT, 256, 0, stream>>>(txt2, xm2_txt, mod_txt, 9216, 12288);

  // mlp1: NT=96, MT=10 -> 960 blocks
  gemm7_kernel<1><<<960, 256, 0, stream>>>(
      xm2_img, img_mlp_w1, img_mlp_b1, nullptr, nullptr, h_img,
      xm2_txt, txt_mlp_w1, txt_mlp_b1, nullptr, nullptr, h_txt,
      8, 2, N_MLP, D_MODEL, D_MODEL);

  // mlp2: NT=24, MT=10, ksplit2 -> 480 blocks, Kper=6144
  gemm7_kernel<3><<<480, 256, 0, stream>>>(
      h_img, img_mlp_w2, img_mlp_b2, out_img, m2slab1, nullptr,
      h_txt, txt_mlp_w2, txt_mlp_b2, out_txt, m2slab1 + (size_t)L_IMG * D_MODEL, nullptr,
      8, 2, D_MODEL, N_MLP, 6144);
  split_reduce_kernel<<<3072, 256, 0, stream>>>(
      out_img, m2slab1, img2, img_mlp_b2, mod_img + 15360, out_img, L_IMG * 768, 768);
  split_reduce_kernel<<<768, 256, 0, stream>>>(
      out_txt, m2slab1 + (size_t)L_IMG * D_MODEL, txt2, txt_mlp_b2, mod_txt + 15360, out_txt, L_TXT * 768, 768);
}

// Round 8
// 910.093 us; speedup vs baseline: 1.3145x; 1.3145x over previous
//
#include <hip/hip_runtime.h>
#include <hip/hip_bf16.h>
#include <math.h>

#define D_MODEL 3072
#define N_HEADS 24
#define DH 128
#define L_TXT 256
#define L_IMG 1024
#define L_ALL 1280
#define N_QKV 9216
#define N_MLP 12288
#define MOD_N 18432

typedef __attribute__((ext_vector_type(4))) float f32x4;
typedef __attribute__((ext_vector_type(8))) short bf16x8;

static __device__ __forceinline__ unsigned short f2bf(float f) {
  __hip_bfloat16 h = __float2bfloat16(f);
  union { __hip_bfloat16 h; unsigned short u; } v; v.h = h;
  return v.u;
}
static __device__ __forceinline__ unsigned pack2(float a, float b) {
  return (unsigned)f2bf(a) | ((unsigned)f2bf(b) << 16);
}

// ---------------------------------------------------------------- small ops
__global__ void silu_kernel(const float* __restrict__ vec, float* __restrict__ s) {
  int i = blockIdx.x * 256 + threadIdx.x;
  if (i < D_MODEL) { float x = vec[i]; s[i] = x / (1.f + expf(-x)); }
}

// float4-vectorized: thread owns 4 consecutive cols. grid (18, 16, 2)
__global__ __launch_bounds__(256) void mod_gemv_partial(
    const float* __restrict__ s, const float* __restrict__ w_img,
    const float* __restrict__ w_txt, float* __restrict__ part) {
  int col4 = blockIdx.x * 256 + threadIdx.x;  // 0..4607
  int kb = blockIdx.y;
  const float4* w4 = (const float4*)(blockIdx.z == 0 ? w_img : w_txt);
  float4 acc = {0.f, 0.f, 0.f, 0.f};
  int k0 = kb * 192;
  #pragma unroll 4
  for (int j = 0; j < 192; ++j) {
    float sv = s[k0 + j];
    float4 wv = w4[(size_t)(k0 + j) * 4608 + col4];
    acc.x = fmaf(sv, wv.x, acc.x);
    acc.y = fmaf(sv, wv.y, acc.y);
    acc.z = fmaf(sv, wv.z, acc.z);
    acc.w = fmaf(sv, wv.w, acc.w);
  }
  ((float4*)part)[(size_t)(blockIdx.z * 16 + kb) * 4608 + col4] = acc;
}

__global__ void mod_reduce(const float* __restrict__ part,
                           const float* __restrict__ b_img,
                           const float* __restrict__ b_txt,
                           float* __restrict__ modv) {
  int i = blockIdx.x * 256 + threadIdx.x;
  int st = i / MOD_N, col = i - st * MOD_N;
  float a = (st == 0) ? b_img[col] : b_txt[col];
  #pragma unroll
  for (int p = 0; p < 16; ++p) a += part[(st * 16 + p) * MOD_N + col];
  modv[i] = a;
}

// LN over D=3072 then (1+scale)*ln + shift, write bf16
__global__ __launch_bounds__(256) void ln_mod_kernel(
    const float* __restrict__ x, unsigned short* __restrict__ xm,
    const float* __restrict__ modv, int sh_off, int sc_off) {
  int row = blockIdx.x, t = threadIdx.x;
  int lane = t & 63, wid = t >> 6;
  const float4* xr = (const float4*)(x + (size_t)row * D_MODEL);
  float4 a = xr[t], b = xr[t + 256], c = xr[t + 512];
  float s = a.x + a.y + a.z + a.w + b.x + b.y + b.z + b.w + c.x + c.y + c.z + c.w;
  float q = a.x * a.x + a.y * a.y + a.z * a.z + a.w * a.w
          + b.x * b.x + b.y * b.y + b.z * b.z + b.w * b.w
          + c.x * c.x + c.y * c.y + c.z * c.z + c.w * c.w;
  #pragma unroll
  for (int m = 1; m < 64; m <<= 1) { s += __shfl_xor(s, m); q += __shfl_xor(q, m); }
  __shared__ float red[8];
  if (lane == 0) { red[wid] = s; red[4 + wid] = q; }
  __syncthreads();
  s = red[0] + red[1] + red[2] + red[3];
  q = red[4] + red[5] + red[6] + red[7];
  float mean = s * (1.f / 3072.f);
  float var = q * (1.f / 3072.f) - mean * mean;
  float inv = 1.f / sqrtf(var + 1e-6f);
  const float4* shp = (const float4*)(modv + sh_off);
  const float4* scp = (const float4*)(modv + sc_off);
  uint2* outp = (uint2*)(xm + (size_t)row * D_MODEL);
  float4 vals[3] = {a, b, c};
  #pragma unroll
  for (int j = 0; j < 3; ++j) {
    float4 sh = shp[t + j * 256], sc = scp[t + j * 256];
    float4 v = vals[j];
    float y0 = (v.x - mean) * inv * (1.f + sc.x) + sh.x;
    float y1 = (v.y - mean) * inv * (1.f + sc.y) + sh.y;
    float y2 = (v.z - mean) * inv * (1.f + sc.z) + sh.z;
    float y3 = (v.w - mean) * inv * (1.f + sc.w) + sh.w;
    uint2 o; o.x = pack2(y0, y1); o.y = pack2(y2, y3);
    outp[t + j * 256] = o;
  }
}

// ---------------------------------------------------------------- GEMM v8
// Hybrid of v6 (A via global_load_lds, prefetched one K-step ahead) and v7
// (W reg-staged: coalesced f32 loads -> cvt_pk -> ds_write_b128 into k-octet
// LDS, 2-deep register prefetch wA/wB). ALL LDS fragment ops are b128 at the
// bank floor:
//   A LDS: linear [row][32k] 64B rows; source pre-swizzle chunk=(l&3)^((l>>3)&3),
//     read slot = lk ^ ((lm>>1)&3)  -> 8 accesses/bank-quad (floor).
//   W LDS: [koct][n][8] bf16, 16B pad per koct row (stride 2064B) -> uniform.
// 256 thr / 4 waves, tile 128M x 128N, BK=32, one barrier per K-step,
// double-buffered. ~33KB LDS, 3 waves/SIMD.
// EPI 0: +bias -> f32   EPI 1: +bias, gelu -> bf16   EPI 3: raw partial -> f32
template <int EPI>
__global__ __launch_bounds__(256, 3) void gemm8_kernel(
    const unsigned short* __restrict__ A0, const float* __restrict__ W0,
    const float* __restrict__ b0, float* __restrict__ oF0,
    float* __restrict__ oF0b, unsigned short* __restrict__ oB0,
    const unsigned short* __restrict__ A1, const float* __restrict__ W1,
    const float* __restrict__ b1, float* __restrict__ oF1,
    float* __restrict__ oF1b, unsigned short* __restrict__ oB1,
    int mi, int mt, int N, int Ktot, int Kper) {
  __shared__ __align__(16) unsigned short Alds[2][4096]; // 128 rows x 64B
  __shared__ __align__(16) unsigned short Wlds[2][4128]; // 4 kocts x 1032

  const int MT = mi + mt;
  const int q8 = gridDim.x >> 3;  // grid % 8 == 0 by construction
  int orig = (blockIdx.x & 7) * q8 + (blockIdx.x >> 3);
  const int per_k = (N >> 7) * MT;
  const int kz = orig / per_k; orig -= kz * per_k;
  const int ntile = orig / MT;
  const int mrem = orig - ntile * MT;

  const unsigned short* A; const float* W; const float* bias;
  float* outF; unsigned short* outB; int brow;
  if (mrem < mi) {
    A = A0; W = W0; bias = b0; outF = kz ? oF0b : oF0; outB = oB0; brow = mrem * 128;
  } else {
    A = A1; W = W1; bias = b1; outF = kz ? oF1b : oF1; outB = oB1; brow = (mrem - mi) * 128;
  }
  const int bcol = ntile * 128;
  const int k0base = kz * Kper;

  const int tid = threadIdx.x, lane = tid & 63, wid = tid >> 6;
  const int lm = lane & 15, lk = lane >> 4;
  const int wr = (wid >> 1) * 64, wc = (wid & 1) * 64;
  const int aslot = lk ^ ((lm >> 1) & 3);

  // A staging: thread handles instrs u = wid*2, wid*2+1 (16 rows each)
  const int arw = lane >> 2;                       // row within instr
  const int achk = (lane & 3) ^ ((lane >> 3) & 3); // pre-swizzled source chunk
  // W staging: koct cells koct0, koct0+2 at column ncol
  const int koct0 = tid >> 7;
  const int ncol = tid & 127;
  const size_t Ns = (size_t)N;
  const float* wgp = W + bcol + ncol;

  f32x4 acc[4][4] = {};
  float wA[16], wB[16];
  const int nt = Kper >> 5;

  auto STAGE_A = [&](int buf, int t) {
    const int kc = k0base + t * 32 + achk * 8;
    #pragma unroll
    for (int u = 0; u < 2; ++u) {
      const int j = wid * 2 + u;
      const unsigned short* g = A + (size_t)(brow + j * 16 + arw) * Ktot + kc;
      __builtin_amdgcn_global_load_lds(g, &Alds[buf][j * 512], 16, 0, 0);
    }
  };
  auto LOADW = [&](float (&w)[16], int t) {
    const size_t kb = (size_t)(k0base + t * 32) * Ns;
    #pragma unroll
    for (int c = 0; c < 2; ++c) {
      const size_t cb = kb + (size_t)((koct0 + 2 * c) * 8) * Ns;
      #pragma unroll
      for (int i = 0; i < 8; ++i)
        w[c * 8 + i] = wgp[cb + (size_t)i * Ns];
    }
  };
  auto PACKW = [&](int buf, float (&w)[16]) {
    #pragma unroll
    for (int c = 0; c < 2; ++c) {
      uint4 p;
      p.x = pack2(w[c * 8 + 0], w[c * 8 + 1]);
      p.y = pack2(w[c * 8 + 2], w[c * 8 + 3]);
      p.z = pack2(w[c * 8 + 4], w[c * 8 + 5]);
      p.w = pack2(w[c * 8 + 6], w[c * 8 + 7]);
      *(uint4*)&Wlds[buf][(koct0 + 2 * c) * 1032 + ncol * 8] = p;
    }
  };
  auto COMPUTE = [&](int buf) {
    bf16x8 bfr[4], af[4];
    #pragma unroll
    for (int nf = 0; nf < 4; ++nf)
      bfr[nf] = *(const bf16x8*)&Wlds[buf][lk * 1032 + (wc + nf * 16 + lm) * 8];
    #pragma unroll
    for (int mf = 0; mf < 4; ++mf) {
      const int row = wr + mf * 16 + lm;
      af[mf] = *(const bf16x8*)&Alds[buf][row * 32 + aslot * 8];
    }
    #pragma unroll
    for (int mf = 0; mf < 4; ++mf)
      #pragma unroll
      for (int nf = 0; nf < 4; ++nf)
        acc[mf][nf] = __builtin_amdgcn_mfma_f32_16x16x32_bf16(af[mf], bfr[nf], acc[mf][nf], 0, 0, 0);
  };

  // prologue
  LOADW(wA, 0);
  LOADW(wB, 1);
  STAGE_A(0, 0);
  PACKW(0, wA);
  __syncthreads();
  for (int t = 0; t < nt; t += 2) {
    STAGE_A(1, t + 1);
    if (t + 2 < nt) LOADW(wA, t + 2);
    PACKW(1, wB);
    COMPUTE(0);
    __syncthreads();
    if (t + 2 < nt) {
      STAGE_A(0, t + 2);
      if (t + 3 < nt) LOADW(wB, t + 3);
      PACKW(0, wA);
    }
    COMPUTE(1);
    __syncthreads();
  }

  #pragma unroll
  for (int nf = 0; nf < 4; ++nf) {
    int c = bcol + wc + nf * 16 + lm;
    float bv = (EPI == 3) ? 0.f : bias[c];
    #pragma unroll
    for (int mf = 0; mf < 4; ++mf) {
      int r0 = brow + wr + mf * 16 + lk * 4;
      #pragma unroll
      for (int rg = 0; rg < 4; ++rg) {
        float v = acc[mf][nf][rg] + bv;
        size_t idx = (size_t)(r0 + rg) * N + c;
        if (EPI == 0) {
          outF[idx] = v;
        } else if (EPI == 1) {
          float g = 0.5f * v * (1.f + tanhf(0.7978845608028654f * (v + 0.044715f * v * v * v)));
          outB[idx] = f2bf(g);
        } else {
          outF[idx] = v;
        }
      }
    }
  }
}

// out = res + gate * (s0 + s1 + bias), float4-vectorized
__global__ __launch_bounds__(256) void split_reduce_kernel(
    const float* __restrict__ s0, const float* __restrict__ s1,
    const float* __restrict__ res, const float* __restrict__ bias,
    const float* __restrict__ gate, float* __restrict__ out,
    int n4, int ncol4) {
  int i = blockIdx.x * 256 + threadIdx.x;
  if (i >= n4) return;
  int c4 = i % ncol4;
  float4 a = ((const float4*)s0)[i];
  float4 b = ((const float4*)s1)[i];
  float4 bv = ((const float4*)bias)[c4];
  float4 gv = ((const float4*)gate)[c4];
  float4 rv = ((const float4*)res)[i];
  float4 o;
  o.x = rv.x + gv.x * (a.x + b.x + bv.x);
  o.y = rv.y + gv.y * (a.y + b.y + bv.y);
  o.z = rv.z + gv.z * (a.z + b.z + bv.z);
  o.w = rv.w + gv.w * (a.w + b.w + bv.w);
  ((float4*)out)[i] = o;
}

// ---------------------------------------------------------------- rms+rope+pack
__global__ __launch_bounds__(256) void rms_rope_kernel(
    const float* __restrict__ qkv_img, const float* __restrict__ qkv_txt,
    const float* __restrict__ img_qn, const float* __restrict__ img_kn,
    const float* __restrict__ txt_qn, const float* __restrict__ txt_kn,
    const float* __restrict__ pe, unsigned short* __restrict__ qa,
    unsigned short* __restrict__ ka, unsigned short* __restrict__ va) {
  int l = blockIdx.x * 4 + (threadIdx.x >> 6);
  int h = blockIdx.y;
  int t = threadIdx.x & 63;
  const float* base; const float* qn; const float* kn;
  if (l < L_TXT) { base = qkv_txt + (size_t)l * N_QKV; qn = txt_qn; kn = txt_kn; }
  else { base = qkv_img + (size_t)(l - L_TXT) * N_QKV; qn = img_qn; kn = img_kn; }
  int d0 = 2 * t;
  float q0 = base[h * DH + d0], q1 = base[h * DH + d0 + 1];
  float k0 = base[D_MODEL + h * DH + d0], k1 = base[D_MODEL + h * DH + d0 + 1];
  float v0 = base[2 * D_MODEL + h * DH + d0], v1 = base[2 * D_MODEL + h * DH + d0 + 1];
  float sq = q0 * q0 + q1 * q1, sk = k0 * k0 + k1 * k1;
  #pragma unroll
  for (int m = 1; m < 64; m <<= 1) { sq += __shfl_xor(sq, m); sk += __shfl_xor(sk, m); }
  float rq = 1.f / sqrtf(sq * (1.f / 128.f) + 1e-6f);
  float rk = 1.f / sqrtf(sk * (1.f / 128.f) + 1e-6f);
  q0 *= rq * qn[d0]; q1 *= rq * qn[d0 + 1];
  k0 *= rk * kn[d0]; k1 *= rk * kn[d0 + 1];
  const float* p = pe + ((size_t)l * 64 + t) * 4;
  float p00 = p[0], p01 = p[1], p10 = p[2], p11 = p[3];
  const float sc = 0.08838834764831845f; // 1/sqrt(128), folded into q
  float Q0 = (p00 * q0 + p01 * q1) * sc;
  float Q1 = (p10 * q0 + p11 * q1) * sc;
  float K0 = p00 * k0 + p01 * k1;
  float K1 = p10 * k0 + p11 * k1;
  size_t o = ((size_t)h * L_ALL + l) * 64 + t;
  ((unsigned*)qa)[o] = pack2(Q0, Q1);
  ((unsigned*)ka)[o] = pack2(K0, K1);
  ((unsigned*)va)[o] = pack2(v0, v1);
}

// ---------------------------------------------------------------- attention
static __device__ __forceinline__ void stage_v8(unsigned short* vp, int n0, uint4 v) {
  vp[(n0 + 0) * 8] = (unsigned short)v.x; vp[(n0 + 1) * 8] = (unsigned short)(v.x >> 16);
  vp[(n0 + 2) * 8] = (unsigned short)v.y; vp[(n0 + 3) * 8] = (unsigned short)(v.y >> 16);
  vp[(n0 + 4) * 8] = (unsigned short)v.z; vp[(n0 + 5) * 8] = (unsigned short)(v.z >> 16);
  vp[(n0 + 6) * 8] = (unsigned short)v.w; vp[(n0 + 7) * 8] = (unsigned short)(v.w >> 16);
}

__global__ __launch_bounds__(256) void attn_kernel(
    const unsigned short* __restrict__ qa, const unsigned short* __restrict__ ka,
    const unsigned short* __restrict__ va, unsigned short* __restrict__ out) {
  __shared__ __align__(16) unsigned short Ks[64 * 136];
  __shared__ __align__(16) unsigned short Vs[16 * 128 * 8]; // [kv/8][d][kv&7]
  __shared__ __align__(16) unsigned short Ps[4][16 * 72];
  int h = blockIdx.y, qt = blockIdx.x;
  int tid = threadIdx.x, lane = tid & 63, wid = tid >> 6;
  int lm = lane & 15, lk = lane >> 4;
  const unsigned short* qh = qa + (size_t)h * L_ALL * DH;
  const unsigned short* kh = ka + (size_t)h * L_ALL * DH;
  const unsigned short* vh = va + (size_t)h * L_ALL * DH;

  int qrow = qt * 64 + wid * 16 + lm;
  bf16x8 qf[4];
  #pragma unroll
  for (int kk = 0; kk < 4; ++kk)
    qf[kk] = *(const bf16x8*)(qh + (size_t)qrow * DH + kk * 32 + lk * 8);

  float m_run[4] = {-INFINITY, -INFINITY, -INFINITY, -INFINITY};
  float s_run[4] = {0.f, 0.f, 0.f, 0.f};
  f32x4 o[8] = {};

  int sr = tid >> 2, sc = (tid & 3) * 32; // staging: row, col0 (elems)

  for (int kt = 0; kt < L_ALL / 64; ++kt) {
    const uint4* kg = (const uint4*)(kh + (size_t)(kt * 64 + sr) * DH + sc);
    uint4 kv0 = kg[0], kv1 = kg[1], kv2 = kg[2], kv3 = kg[3];
    const uint4* vg = (const uint4*)(vh + (size_t)(kt * 64 + sr) * DH + sc);
    uint4 vv0 = vg[0], vv1 = vg[1], vv2 = vg[2], vv3 = vg[3];
    __syncthreads();
    uint4* kd = (uint4*)(&Ks[sr * 136 + sc]);
    kd[0] = kv0; kd[1] = kv1; kd[2] = kv2; kd[3] = kv3;
    {
      unsigned short* vp = &Vs[(sr >> 3) * 1024 + (sr & 7)];
      stage_v8(vp, sc, vv0); stage_v8(vp, sc + 8, vv1);
      stage_v8(vp, sc + 16, vv2); stage_v8(vp, sc + 24, vv3);
    }
    __syncthreads();

    f32x4 S[4] = {};
    #pragma unroll
    for (int kk = 0; kk < 4; ++kk)
      #pragma unroll
      for (int nf = 0; nf < 4; ++nf) {
        bf16x8 bv = *(const bf16x8*)(&Ks[(nf * 16 + lm) * 136 + kk * 32 + lk * 8]);
        S[nf] = __builtin_amdgcn_mfma_f32_16x16x32_bf16(qf[kk], bv, S[nf], 0, 0, 0);
      }

    float corr[4];
    #pragma unroll
    for (int r = 0; r < 4; ++r) {
      float mx = fmaxf(fmaxf(S[0][r], S[1][r]), fmaxf(S[2][r], S[3][r]));
      mx = fmaxf(mx, __shfl_xor(mx, 1));
      mx = fmaxf(mx, __shfl_xor(mx, 2));
      mx = fmaxf(mx, __shfl_xor(mx, 4));
      mx = fmaxf(mx, __shfl_xor(mx, 8));
      float mn = fmaxf(m_run[r], mx);
      corr[r] = expf(m_run[r] - mn);
      m_run[r] = mn;
    }
    float rs[4] = {0.f, 0.f, 0.f, 0.f};
    float pv[4][4];
    #pragma unroll
    for (int nf = 0; nf < 4; ++nf)
      #pragma unroll
      for (int r = 0; r < 4; ++r) {
        pv[nf][r] = expf(S[nf][r] - m_run[r]);
        rs[r] += pv[nf][r];
      }
    #pragma unroll
    for (int nf = 0; nf < 4; ++nf)
      #pragma unroll
      for (int r = 0; r < 4; ++r)
        Ps[wid][(lk * 4 + r) * 72 + nf * 16 + lm] = f2bf(pv[nf][r]);
    #pragma unroll
    for (int r = 0; r < 4; ++r) {
      rs[r] += __shfl_xor(rs[r], 1);
      rs[r] += __shfl_xor(rs[r], 2);
      rs[r] += __shfl_xor(rs[r], 4);
      rs[r] += __shfl_xor(rs[r], 8);
      s_run[r] = s_run[r] * corr[r] + rs[r];
    }
    #pragma unroll
    for (int nf = 0; nf < 8; ++nf)
      #pragma unroll
      for (int r = 0; r < 4; ++r)
        o[nf][r] *= corr[r];

    #pragma unroll
    for (int kk2 = 0; kk2 < 2; ++kk2) {
      bf16x8 pa = *(const bf16x8*)(&Ps[wid][lm * 72 + kk2 * 32 + lk * 8]);
      #pragma unroll
      for (int nf = 0; nf < 8; ++nf) {
        bf16x8 vb = *(const bf16x8*)(&Vs[((kk2 * 4 + lk) * 128 + nf * 16 + lm) * 8]);
        o[nf] = __builtin_amdgcn_mfma_f32_16x16x32_bf16(pa, vb, o[nf], 0, 0, 0);
      }
    }
  }

  float inv[4];
  #pragma unroll
  for (int r = 0; r < 4; ++r) inv[r] = 1.f / s_run[r];
  #pragma unroll
  for (int nf = 0; nf < 8; ++nf)
    #pragma unroll
    for (int r = 0; r < 4; ++r) {
      int row = qt * 64 + wid * 16 + lk * 4 + r;
      int col = h * DH + nf * 16 + lm;
      out[(size_t)row * D_MODEL + col] = f2bf(o[nf][r] * inv[r]);
    }
}

// ---------------------------------------------------------------- launch
extern "C" void kernel_launch(void* const* d_in, const int* in_sizes, int n_in,
                              void* d_out, int out_size, void* d_ws, size_t ws_size,
                              hipStream_t stream) {
  const float* img = (const float*)d_in[0];
  const float* txt = (const float*)d_in[1];
  const float* vec = (const float*)d_in[2];
  const float* pe = (const float*)d_in[3];
  const float* img_mod_w = (const float*)d_in[4];
  const float* img_mod_b = (const float*)d_in[5];
  const float* img_qkv_w = (const float*)d_in[6];
  const float* img_qkv_b = (const float*)d_in[7];
  const float* img_qnorm = (const float*)d_in[8];
  const float* img_knorm = (const float*)d_in[9];
  const float* img_proj_w = (const float*)d_in[10];
  const float* img_proj_b = (const float*)d_in[11];
  const float* img_mlp_w1 = (const float*)d_in[12];
  const float* img_mlp_b1 = (const float*)d_in[13];
  const float* img_mlp_w2 = (const float*)d_in[14];
  const float* img_mlp_b2 = (const float*)d_in[15];
  const float* txt_mod_w = (const float*)d_in[16];
  const float* txt_mod_b = (const float*)d_in[17];
  const float* txt_qkv_w = (const float*)d_in[18];
  const float* txt_qkv_b = (const float*)d_in[19];
  const float* txt_qnorm = (const float*)d_in[20];
  const float* txt_knorm = (const float*)d_in[21];
  const float* txt_proj_w = (const float*)d_in[22];
  const float* txt_proj_b = (const float*)d_in[23];
  const float* txt_mlp_w1 = (const float*)d_in[24];
  const float* txt_mlp_b1 = (const float*)d_in[25];
  const float* txt_mlp_w2 = (const float*)d_in[26];
  const float* txt_mlp_b2 = (const float*)d_in[27];

  char* wsb = (char*)d_ws;
  float* silu_s = (float*)(wsb + 0);
  float* part = (float*)(wsb + 16384);
  float* modv = (float*)(wsb + 2375680);
  unsigned short* xm_img = (unsigned short*)(wsb + 2523136);
  unsigned short* xm_txt = xm_img + (size_t)L_IMG * D_MODEL;
  float* qkv_img = (float*)(wsb + 10387456);
  float* qkv_txt = qkv_img + (size_t)L_IMG * N_QKV;
  unsigned short* qa = (unsigned short*)(wsb + 57573376);
  unsigned short* ka = (unsigned short*)(wsb + 65437696);
  unsigned short* va = (unsigned short*)(wsb + 73302016);
  unsigned short* attn = xm_img;                       // xm dead
  float* img2 = (float*)(wsb + 10387456);              // qkv dead
  float* txt2 = img2 + (size_t)L_IMG * D_MODEL;
  float* pslab = (float*)(wsb + 26116096);             // proj partials (2x 15.73MB)
  float* pslab1 = pslab + (size_t)L_ALL * D_MODEL;
  unsigned short* h_img = (unsigned short*)(wsb + 26116096); // after proj reduce
  unsigned short* h_txt = h_img + (size_t)L_IMG * N_MLP;
  unsigned short* xm2_img = qa;                        // qa dead after attn
  unsigned short* xm2_txt = xm2_img + (size_t)L_IMG * D_MODEL;
  float* m2slab1 = (float*)(wsb + 57573376);           // mlp2 slab1 (xm2 dead)
  float* out_img = (float*)d_out;
  float* out_txt = out_img + (size_t)L_IMG * D_MODEL;
  float* mod_img = modv;
  float* mod_txt = modv + MOD_N;

  silu_kernel<<<12, 256, 0, stream>>>(vec, silu_s);
  mod_gemv_partial<<<dim3(18, 16, 2), 256, 0, stream>>>(silu_s, img_mod_w, txt_mod_w, part);
  mod_reduce<<<144, 256, 0, stream>>>(part, img_mod_b, txt_mod_b, modv);
  ln_mod_kernel<<<L_IMG, 256, 0, stream>>>(img, xm_img, mod_img, 0, 3072);
  ln_mod_kernel<<<L_TXT, 256, 0, stream>>>(txt, xm_txt, mod_txt, 0, 3072);

  // qkv: NT=72, MT=10 -> 720 blocks
  gemm8_kernel<0><<<720, 256, 0, stream>>>(
      xm_img, img_qkv_w, img_qkv_b, qkv_img, qkv_img, nullptr,
      xm_txt, txt_qkv_w, txt_qkv_b, qkv_txt, qkv_txt, nullptr,
      8, 2, N_QKV, D_MODEL, D_MODEL);

  rms_rope_kernel<<<dim3(L_ALL / 4, N_HEADS), 256, 0, stream>>>(qkv_img, qkv_txt, img_qnorm, img_knorm, txt_qnorm, txt_knorm, pe, qa, ka, va);
  attn_kernel<<<dim3(L_ALL / 64, N_HEADS), 256, 0, stream>>>(qa, ka, va, attn);

  // proj: NT=24, MT=10, ksplit2 -> 480 blocks, Kper=1536
  gemm8_kernel<3><<<480, 256, 0, stream>>>(
      attn + (size_t)L_TXT * D_MODEL, img_proj_w, img_proj_b, pslab, pslab1, nullptr,
      attn, txt_proj_w, txt_proj_b, pslab + (size_t)L_IMG * D_MODEL, pslab1 + (size_t)L_IMG * D_MODEL, nullptr,
      8, 2, D_MODEL, D_MODEL, 1536);
  split_reduce_kernel<<<3072, 256, 0, stream>>>(
      pslab, pslab1, img, img_proj_b, mod_img + 6144, img2, L_IMG * 768, 768);
  split_reduce_kernel<<<768, 256, 0, stream>>>(
      pslab + (size_t)L_IMG * D_MODEL, pslab1 + (size_t)L_IMG * D_MODEL, txt, txt_proj_b, mod_txt + 6144, txt2, L_TXT * 768, 768);

  ln_mod_kernel<<<L_IMG, 256, 0, stream>>>(img2, xm2_img, mod_img, 9216, 12288);
  ln_mod_kernel<<<L_TXT, 256, 0, stream>>>(txt2, xm2_txt, mod_txt, 9216, 12288);

  // mlp1: NT=96, MT=10 -> 960 blocks
  gemm8_kernel<1><<<960, 256, 0, stream>>>(
      xm2_img, img_mlp_w1, img_mlp_b1, nullptr, nullptr, h_img,
      xm2_txt, txt_mlp_w1, txt_mlp_b1, nullptr, nullptr, h_txt,
      8, 2, N_MLP, D_MODEL, D_MODEL);

  // mlp2: NT=24, MT=10, ksplit2 -> 480 blocks, Kper=6144
  gemm8_kernel<3><<<480, 256, 0, stream>>>(
      h_img, img_mlp_w2, img_mlp_b2, out_img, m2slab1, nullptr,
      h_txt, txt_mlp_w2, txt_mlp_b2, out_txt, m2slab1 + (size_t)L_IMG * D_MODEL, nullptr,
      8, 2, D_MODEL, N_MLP, 6144);
  split_reduce_kernel<<<3072, 256, 0, stream>>>(
      out_img, m2slab1, img2, img_mlp_b2, mod_img + 15360, out_img, L_IMG * 768, 768);
  split_reduce_kernel<<<768, 256, 0, stream>>>(
      out_txt, m2slab1 + (size_t)L_IMG * D_MODEL, txt2, txt_mlp_b2, mod_txt + 15360, out_txt, L_TXT * 768, 768);
}